// Round 10
// baseline (169.922 us; speedup 1.0000x reference)
//
#include <hip/hip_runtime.h>
#include <math.h>

typedef _Float16 half8  __attribute__((ext_vector_type(8)));
typedef __fp16   fp16x2 __attribute__((ext_vector_type(2)));
typedef float    f32x4  __attribute__((ext_vector_type(4)));
typedef float    f32x16 __attribute__((ext_vector_type(16)));
typedef int      int4v  __attribute__((ext_vector_type(4)));

// weight layout (halfs), 32x32x16 A-fragments: A[m][k], m = MT*32+(lane&31),
// k = s*16+(lane>>5)*8+j
// W1: [MT(8)][lane(64)][j(8)]           = 4096  (k<2 real, rest 0)
// W2/W3: [MT(8)][s(16)][lane(64)][j(8)] = 65536 each
// W4: [s(16)][lane(64)][j(8)]           = 8192  (m<3 real, rest 0)
#define W1OFF 0
#define W2OFF 4096
#define W3OFF 69632
#define W4OFF 135168
#define SWTOT 143360
#define OUT_PIX (16*128*128)

// ---------------- prep: swizzle weights (fp32 -> f16 frag-contiguous) + dx/dy tail ----
__global__ void inr_prep(const float* __restrict__ W1, const float* __restrict__ W2,
                         const float* __restrict__ W3, const float* __restrict__ W4,
                         const int* __restrict__ sidx, const float* __restrict__ sv,
                         _Float16* __restrict__ wsw, float* __restrict__ outtail)
{
    int tid = blockIdx.x * 256 + threadIdx.x;
    if (tid < 16) {
        int si = sidx[tid];
        outtail[tid]      = sv[2*si + 1];   // dx = shift[:,1]
        outtail[16 + tid] = sv[2*si + 0];   // dy = shift[:,0]
    }
    if (tid >= SWTOT) return;
    int kind, rel;
    if      (tid < W2OFF) { kind = 0; rel = tid; }
    else if (tid < W3OFF) { kind = 1; rel = tid - W2OFF; }
    else if (tid < W4OFF) { kind = 2; rel = tid - W3OFF; }
    else                  { kind = 3; rel = tid - W4OFF; }
    int j    = rel & 7;
    int lane = (rel >> 3) & 63;
    int blk  = rel >> 9;
    int m32  = lane & 31;
    int hsel = lane >> 5;
    float val;
    if (kind == 3) {                       // blk = s; W4: A[m][k]=W4[k][m], m<3 else 0
        int k = blk*16 + hsel*8 + j;
        val = (m32 < 3) ? W4[k*3 + m32] : 0.0f;
    } else if (kind == 0) {                // blk = MT; K padded 2->16
        int m = blk*32 + m32;
        int k = hsel*8 + j;
        val = (k < 2) ? W1[k*256 + m] : 0.0f;
    } else {                               // blk = MT*16 + s   ([MT][s] layout)
        int MT = blk >> 4, s = blk & 15;
        int m = MT*32 + m32;
        int k = s*16 + hsel*8 + j;
        val = (kind == 1) ? W2[k*256 + m] : W3[k*256 + m];
    }
    wsw[tid] = (_Float16)val;
}

// ---------------- register-resident MLP, no barriers ----------------
// Wave owns N=32 pixels end-to-end.  h lives as B-fragments: B[s][j] =
// h[hid = 16s + 8*hsel + j] for pixel (lane&31).
// C->B transpose (derived from validated 32x32x16 layouts):
//   B[s] low4  = acc-quad (2(s&1)+hsel) of Mtile (s>>1) from hsel=0 lane,
//   B[s] high4 = same quad from hsel=1 lane           -> one shfl_xor(32).
__device__ __forceinline__ void epi(const f32x16& acc, const float* __restrict__ bias,
                                    int mt, half8 (&Bout)[16], int hsel)
{
    int ipk[8];
#pragma unroll
    for (int q = 0; q < 4; ++q) {          // quad q = acc regs 4q..4q+3 = rows 8q+4*hsel..+3
        f32x4 bv = *(const f32x4*)&bias[32*mt + 8*q + 4*hsel];
        fp16x2 lo = __builtin_amdgcn_cvt_pkrtz(fmaxf(acc[4*q+0] + bv[0], 0.f),
                                               fmaxf(acc[4*q+1] + bv[1], 0.f));
        fp16x2 hi = __builtin_amdgcn_cvt_pkrtz(fmaxf(acc[4*q+2] + bv[2], 0.f),
                                               fmaxf(acc[4*q+3] + bv[3], 0.f));
        ipk[2*q]   = __builtin_bit_cast(int, lo);
        ipk[2*q+1] = __builtin_bit_cast(int, hi);
    }
#pragma unroll
    for (int P = 0; P < 2; ++P) {          // s = 2*mt + P
        int s0 = ipk[4*P+0], s1 = ipk[4*P+1];   // own quad 2P   (rows ..+4*hsel)
        int t0 = ipk[4*P+2], t1 = ipk[4*P+3];   // own quad 2P+1
        int send0 = hsel ? s0 : t0;             // partner needs quad 2P+partner_h
        int send1 = hsel ? s1 : t1;
        int x0 = __shfl_xor(send0, 32, 64);
        int x1 = __shfl_xor(send1, 32, 64);
        int4v r;
        r[0] = hsel ? x0 : s0;                  // low4: from hsel=0 lane, quad 2P+hsel
        r[1] = hsel ? x1 : s1;
        r[2] = hsel ? t0 : x0;                  // high4: from hsel=1 lane, quad 2P+hsel
        r[3] = hsel ? t1 : x1;
        Bout[2*mt+P] = __builtin_bit_cast(half8, r);
    }
}

__device__ __forceinline__ void big_layer(const half8* __restrict__ Aw,
                                          const float* __restrict__ bias,
                                          const half8 (&Bin)[16], half8 (&Bout)[16],
                                          int lane, int hsel)
{
#pragma unroll
    for (int mp = 0; mp < 4; ++mp) {       // 2 interleaved acc chains per pair
        f32x16 acc0, acc1;
#pragma unroll
        for (int i = 0; i < 16; ++i) { acc0[i] = 0.f; acc1[i] = 0.f; }
#pragma unroll
        for (int s = 0; s < 16; ++s) {
            half8 a0 = Aw[((2*mp+0)*16 + s)*64 + lane];
            half8 a1 = Aw[((2*mp+1)*16 + s)*64 + lane];
            acc0 = __builtin_amdgcn_mfma_f32_32x32x16_f16(a0, Bin[s], acc0, 0, 0, 0);
            acc1 = __builtin_amdgcn_mfma_f32_32x32x16_f16(a1, Bin[s], acc1, 0, 0, 0);
        }
        epi(acc0, bias, 2*mp+0, Bout, hsel);
        epi(acc1, bias, 2*mp+1, Bout, hsel);
    }
}

__launch_bounds__(256, 2)
__global__ void inr_fused(const float* __restrict__ x, const int* __restrict__ sidx_p,
                          const float* __restrict__ sv, const float* __restrict__ ra,
                          const float* __restrict__ cs, const float* __restrict__ csh,
                          const float* __restrict__ b1, const float* __restrict__ b2,
                          const float* __restrict__ b3, const float* __restrict__ b4,
                          const _Float16* __restrict__ wsw, float* __restrict__ out)
{
    // occupancy shaper: keep the replay-proven resident shape (64 KB, 2 blocks/CU).
    __shared__ _Float16 hdummy[32768];
    int t = threadIdx.x;
    int lane = t & 63, w = t >> 6;
    int p32 = lane & 31, hsel = lane >> 5;
    int pixbase = blockIdx.x * 128;
    int b = pixbase >> 14;                 // 16384 px per image
    int sidx = sidx_p[b];
    float dy = sv[2*sidx], dx = sv[2*sidx + 1];
    float ang = ra[sidx];
    float sn, cn;
    sincosf(ang, &sn, &cn);
    if (sidx == 0x70000000) {              // never true; keeps hdummy allocated
        hdummy[t] = (_Float16)ang;
        __syncthreads();
        out[0] = (float)hdummy[(t + 1) & 255];
    }

    int pix = pixbase + 32*w + p32;
    float xv0 = x[pix*2 + 0];
    float xv1 = x[pix*2 + 1];
    float u = cn*xv0 - sn*xv1 + dx;
    float v = sn*xv0 + cn*xv1 + dy;

    half8 BA[16], BB[16];
    half8 B1;
#pragma unroll
    for (int i = 0; i < 8; ++i) B1[i] = (_Float16)0.0f;
    if (hsel == 0) { B1[0] = (_Float16)u; B1[1] = (_Float16)v; }

    const half8* wsw8 = (const half8*)wsw;

    // layer 1: K=16 (2 real), one MFMA per Mtile
    {
        const half8* A1 = wsw8 + (W1OFF >> 3);
#pragma unroll
        for (int mp = 0; mp < 4; ++mp) {
            f32x16 acc0, acc1;
#pragma unroll
            for (int i = 0; i < 16; ++i) { acc0[i] = 0.f; acc1[i] = 0.f; }
            half8 a0 = A1[(2*mp+0)*64 + lane];
            half8 a1 = A1[(2*mp+1)*64 + lane];
            acc0 = __builtin_amdgcn_mfma_f32_32x32x16_f16(a0, B1, acc0, 0, 0, 0);
            acc1 = __builtin_amdgcn_mfma_f32_32x32x16_f16(a1, B1, acc1, 0, 0, 0);
            epi(acc0, b1, 2*mp+0, BA, hsel);
            epi(acc1, b1, 2*mp+1, BA, hsel);
        }
    }
    big_layer(wsw8 + (W2OFF >> 3), b2, BA, BB, lane, hsel);   // layer 2
    big_layer(wsw8 + (W3OFF >> 3), b3, BB, BA, lane, hsel);   // layer 3

    // layer 4: one 32x32 tile (rows 0..2 real)
    const half8* A4 = wsw8 + (W4OFF >> 3);
    f32x16 a4;
#pragma unroll
    for (int i = 0; i < 16; ++i) a4[i] = 0.f;
#pragma unroll
    for (int s = 0; s < 16; ++s) {
        half8 aw = A4[s*64 + lane];
        a4 = __builtin_amdgcn_mfma_f32_32x32x16_f16(aw, BA[s], a4, 0, 0, 0);
    }
    if (hsel == 0) {                       // regs 0,1,2 = rows 0,1,2; col = p32 = pixel
        bool doc = (sidx != 0);
        float s0 = cs[sidx*3+0], s1 = cs[sidx*3+1], s2 = cs[sidx*3+2];
        float t0 = csh[sidx*3+0], t1 = csh[sidx*3+1], t2 = csh[sidx*3+2];
        float v0 = a4[0] + b4[0];
        float v1 = a4[1] + b4[1];
        float v2 = a4[2] + b4[2];
        if (doc) { v0 = v0*s0 + t0; v1 = v1*s1 + t1; v2 = v2*s2 + t2; }
        out[pix*3 + 0] = v0;
        out[pix*3 + 1] = v1;
        out[pix*3 + 2] = v2;
    }
}

extern "C" void kernel_launch(void* const* d_in, const int* in_sizes, int n_in,
                              void* d_out, int out_size, void* d_ws, size_t ws_size,
                              hipStream_t stream)
{
    const float* x    = (const float*)d_in[0];
    const int*   sidx = (const int*)  d_in[1];
    const float* sv   = (const float*)d_in[2];
    const float* ra   = (const float*)d_in[3];
    const float* cs   = (const float*)d_in[4];
    const float* csh  = (const float*)d_in[5];
    const float* W1   = (const float*)d_in[6];
    const float* b1   = (const float*)d_in[7];
    const float* W2   = (const float*)d_in[8];
    const float* b2   = (const float*)d_in[9];
    const float* W3   = (const float*)d_in[10];
    const float* b3   = (const float*)d_in[11];
    const float* W4   = (const float*)d_in[12];
    const float* b4   = (const float*)d_in[13];
    float* out = (float*)d_out;
    _Float16* wsw = (_Float16*)d_ws;

    inr_prep<<<SWTOT/256, 256, 0, stream>>>(W1, W2, W3, W4, sidx, sv, wsw, out + OUT_PIX*3);
    inr_fused<<<OUT_PIX/128, 256, 0, stream>>>(x, sidx, sv, ra, cs, csh,
                                               b1, b2, b3, b4, wsw, out);
}